// Round 3
// baseline (1612.248 us; speedup 1.0000x reference)
//
#include <hip/hip_runtime.h>

// Correlation cost volume, specialized: B=16, C=256, H=W=96, k=1, d=4, s1=s2=1.
// out[b, (dy+4)*9+(dx+4), y, x] = (1/256) * sum_c x1[b,c,y,x] * x2[b,c,y+dy,x+dx]
// (x2 zero-padded by 4). Thread owns (8-pixel x-strip, one dy, all 9 dx) -> 72 accs.
//
// v4 (on top of v3's chunked 12-float LDS layout):
//  - 2-way channel split (blockIdx.z): 768 uniform blocks (3 half-blocks/CU)
//    instead of 384 (1.5/CU, half the CUs idle after their 1 block).
//    Combine via fp32 atomicAdd after hipMemsetAsync (exact: 2-term fp add
//    is order-independent).
//  - dyi-fastest lane order: x2 read bank-group = (7*(r+dyi)+3s) mod 8 is
//    near-uniform within each 9-lane dyi run (was: 12 strips stride-3 -> 4
//    groups 2-way per dozen, 2.33e7 conflict cycles). x1 reads become 9-lane
//    broadcasts.
//  - double-buffered LDS, ONE barrier per 4-channel stage; loads for stage
//    k+2 issued at end of stage k, written end of stage k+1 -> full-stage
//    latency cover. 2*38.3KB, still 2 blocks/CU resident.
//  - launch_bounds(NT,2): VGPR must stay <=128 (v2 lesson: 64-cap => spill).

namespace {
constexpr int Bsz = 16, Cch = 256, Hh = 96, Ww = 96;
constexpr int Dd = 4, NDisp = 9;            // 2*d+1
constexpr int TH = 4;                       // output rows per block
constexpr int PX = 8;                       // pixels per thread (x)
constexpr int NSTRIP = Ww / PX;             // 12
constexpr int CC = 4;                       // channels per LDS stage
constexpr int X2ROWS = TH + 2 * Dd;         // 12
constexpr int NT = TH * NDisp * NSTRIP;     // 432 threads
constexpr int HW = Hh * Ww;                 // 9216
constexpr int CSPLIT = 2;                   // channel split factor
constexpr int CPB = Cch / CSPLIT;           // 128 channels per block
constexpr int NSTAGE = CPB / CC;            // 32 stages

// chunked layout: 8 payload floats + 4 pad per 12-float chunk
constexpr int CHUNK = 12;
constexpr int X1RP  = (Ww / 8) * CHUNK;     // 144 floats per x1 row
constexpr int X1_LDS = CC * TH * X1RP;      // 2304 floats
constexpr int X2COLS = 104;                 // padded cols stored (need 0..103)
constexpr int X2RP  = (X2COLS / 8) * CHUNK; // 156 floats per x2 row
constexpr int X2_LDS = CC * X2ROWS * X2RP;  // 7488 floats
constexpr int X2_GROUPS = X2COLS / 4;       // 26 float4 groups per padded row
constexpr int X1_F4 = CC * TH * Ww / 4;     // 384 staging items
constexpr int X2_F4 = CC * X2ROWS * X2_GROUPS;  // 1248 items
constexpr int N_ITEMS = X1_F4 + X2_F4;      // 1632 -> <=4 per thread
constexpr int BUF  = X1_LDS + X2_LDS;       // 9792 floats per stage buffer
constexpr int BUFP = BUF + 4;               // + dummy f4 slot (pad items)
}

__global__ __launch_bounds__(NT, 2)
void corr81(const float* __restrict__ x1, const float* __restrict__ x2,
            float* __restrict__ out) {
  __shared__ __align__(16) float lds[2 * BUFP];   // 78.4 KB, double-buffered

  const int t  = threadIdx.x;
  const int y0 = blockIdx.x * TH;
  const int b  = blockIdx.y;
  const int cb = blockIdx.z * CPB;          // channel-half base

  const int r   = t / (NDisp * NSTRIP);     // 0..3  output row within tile
  const int rem = t % (NDisp * NSTRIP);
  const int s   = rem / NDisp;              // 0..11 strip   (dyi fastest!)
  const int dyi = rem % NDisp;              // 0..8  (dy+4)
  const int x0  = s * PX;

  const float* __restrict__ x1b = x1 + ((size_t)b * Cch + cb) * HW;
  const float* __restrict__ x2b = x2 + ((size_t)b * Cch + cb) * HW;

  // ---- precompute staging descriptors (constant 4 slots, mask invalid) ----
  const float* gp[4];
  int  loff[4];
  bool zero[4];
#pragma unroll
  for (int j = 0; j < 4; ++j) {
    int i = t + j * NT;
    if (i >= N_ITEMS) {                     // pad slot: dummy tail of buffer
      gp[j] = x1b; loff[j] = BUF; zero[j] = true;
    } else if (i < X1_F4) {
      int c    = i / (TH * Ww / 4);         // 96 f4 per channel (4 rows)
      int q    = i % (TH * Ww / 4);
      int grow = q / (Ww / 4);              // 0..3 row in tile
      int col  = (q % (Ww / 4)) * 4;        // 0,4,...,92
      gp[j]   = x1b + c * HW + (size_t)(y0 + grow) * Ww + col;
      loff[j] = c * (TH * X1RP) + grow * X1RP + (col >> 3) * CHUNK + (col & 7);
      zero[j] = false;
    } else {
      int m  = i - X1_F4;
      int c  = m / (X2ROWS * X2_GROUPS);
      int m2 = m % (X2ROWS * X2_GROUPS);
      int ry = m2 / X2_GROUPS;              // 0..11 padded row
      int g  = m2 % X2_GROUPS;              // col group: padded cols [4g,4g+3]
      int pc = g * 4;
      int gy = y0 + ry - Dd;
      bool z = (gy < 0) | (gy >= Hh) | (g == 0) | (g == X2_GROUPS - 1);
      gp[j]   = z ? x2b : (x2b + c * HW + gy * Ww + (pc - 4));
      loff[j] = X1_LDS + c * (X2ROWS * X2RP) + ry * X2RP
              + (pc >> 3) * CHUNK + (pc & 7);
      zero[j] = z;
    }
  }

  float acc[NDisp][PX];
#pragma unroll
  for (int i = 0; i < NDisp; ++i)
#pragma unroll
    for (int j = 0; j < PX; ++j) acc[i][j] = 0.f;

  // per-thread LDS read bases within a buffer
  const float* ap0 = lds + r * X1RP + s * CHUNK;
  const float* bp0 = lds + X1_LDS + (r + dyi) * X2RP + s * CHUNK;

  // ---- prologue: stage 0 -> buf0; issue stage-1 loads ----
  float4 v[4];
#pragma unroll
  for (int j = 0; j < 4; ++j)
    v[j] = zero[j] ? make_float4(0.f, 0.f, 0.f, 0.f) : *(const float4*)gp[j];
#pragma unroll
  for (int j = 0; j < 4; ++j)
    *(float4*)(lds + loff[j]) = v[j];
#pragma unroll
  for (int j = 0; j < 4; ++j) {
    gp[j] += CC * HW;
    v[j] = zero[j] ? make_float4(0.f, 0.f, 0.f, 0.f) : *(const float4*)gp[j];
  }
  __syncthreads();

  // ---- main loop: ONE barrier per stage, double-buffered ----
#pragma unroll 2
  for (int k = 0; k < NSTAGE; ++k) {
    const float* ap_b = ap0 + (k & 1) * BUFP;
    const float* bp_b = bp0 + (k & 1) * BUFP;
#pragma unroll
    for (int cc = 0; cc < CC; ++cc) {
      const float* ap = ap_b + cc * (TH * X1RP);
      float a[PX];
      *(float4*)(a)     = *(const float4*)(ap);
      *(float4*)(a + 4) = *(const float4*)(ap + 4);
      const float* bp = bp_b + cc * (X2ROWS * X2RP);
      float bb[PX + 2 * Dd];
      *(float4*)(bb)      = *(const float4*)(bp);             // chunk s   [0..3]
      *(float4*)(bb + 4)  = *(const float4*)(bp + 4);         // chunk s   [4..7]
      *(float4*)(bb + 8)  = *(const float4*)(bp + CHUNK);     // chunk s+1 [0..3]
      *(float4*)(bb + 12) = *(const float4*)(bp + CHUNK + 4); // chunk s+1 [4..7]
#pragma unroll
      for (int dx = 0; dx < NDisp; ++dx)
#pragma unroll
        for (int px = 0; px < PX; ++px)
          acc[dx][px] += a[px] * bb[px + dx];
    }
    // stage k+1 data (loaded a full stage ago) -> other buffer; then issue k+2
    if (k + 1 < NSTAGE) {
      float* wb = lds + ((k + 1) & 1) * BUFP;
#pragma unroll
      for (int j = 0; j < 4; ++j)
        *(float4*)(wb + loff[j]) = v[j];
      if (k + 2 < NSTAGE) {
#pragma unroll
        for (int j = 0; j < 4; ++j) {
          gp[j] += CC * HW;
          v[j] = zero[j] ? make_float4(0.f, 0.f, 0.f, 0.f) : *(const float4*)gp[j];
        }
      }
    }
    __syncthreads();
  }

  // ---- epilogue: accumulate into out (both channel-halves add) ----
  const float nrm = 1.0f / (float)Cch;
  float* ob = out + ((size_t)b * (NDisp * NDisp) + (size_t)dyi * NDisp) * HW
                  + (size_t)(y0 + r) * Ww + x0;
#pragma unroll
  for (int dx = 0; dx < NDisp; ++dx)
#pragma unroll
    for (int px = 0; px < PX; ++px)
      atomicAdd(ob + (size_t)dx * HW + px, acc[dx][px] * nrm);
}

extern "C" void kernel_launch(void* const* d_in, const int* in_sizes, int n_in,
                              void* d_out, int out_size, void* d_ws, size_t ws_size,
                              hipStream_t stream) {
  const float* x1 = (const float*)d_in[0];
  const float* x2 = (const float*)d_in[1];
  float* out = (float*)d_out;
  hipMemsetAsync(d_out, 0, (size_t)out_size, stream);
  dim3 grid(Hh / TH, Bsz, CSPLIT);   // 24 x 16 x 2 = 768 blocks (3/CU uniform)
  dim3 block(NT);                    // 432 threads
  hipLaunchKernelGGL(corr81, grid, block, 0, stream, x1, x2, out);
}

// Round 4
// 997.518 us; speedup vs baseline: 1.6163x; 1.6163x over previous
//
#include <hip/hip_runtime.h>

// Correlation cost volume, specialized: B=16, C=256, H=W=96, k=1, d=4, s1=s2=1.
// out[b, (dy+4)*9+(dx+4), y, x] = (1/256) * sum_c x1[b,c,y,x] * x2[b,c,y+dy,x+dx]
// (x2 zero-padded by 4). Thread owns (8-pixel x-strip, one dy, all 9 dx) -> 72 accs.
//
// v5 = v3's proven loop structure (single LDS buffer, 2 barriers/stage,
//      prefetch-into-regs, 92 VGPR no spill) + two ideas validated in v4:
//  - dyi-fastest lane order: per-work-unit LDS bank conflicts 1.37x lower
//    (x2 row stride 156 floats -> 16B-group stride 7 mod 8 across the 9-lane
//    dyi run; x1 reads become 9-lane broadcasts).
//  - 2-way channel split (blockIdx.z): 768 uniform half-blocks, 2 resident/CU,
//    3 per CU -> makespan ~3/4 of v3's (which left half the CUs idle after
//    their single block). Combine via fp32 atomicAdd after hipMemsetAsync.
//  v4 lesson: NO unroll-2 / double-buffer here — that pushed VGPR demand past
//  128 and spilled acc (WRITE_SIZE 46MB -> 1.8GB, 212 -> 1433us).

namespace {
constexpr int Bsz = 16, Cch = 256, Hh = 96, Ww = 96;
constexpr int Dd = 4, NDisp = 9;            // 2*d+1
constexpr int TH = 4;                       // output rows per block
constexpr int PX = 8;                       // pixels per thread (x)
constexpr int NSTRIP = Ww / PX;             // 12
constexpr int CC = 4;                       // channels per LDS stage
constexpr int X2ROWS = TH + 2 * Dd;         // 12
constexpr int NT = TH * NDisp * NSTRIP;     // 432 threads
constexpr int HW = Hh * Ww;                 // 9216
constexpr int CSPLIT = 2;                   // channel split factor
constexpr int CPB = Cch / CSPLIT;           // 128 channels per block

// chunked layout: 8 payload floats + 4 pad per 12-float chunk
constexpr int CHUNK = 12;
constexpr int X1RP  = (Ww / 8) * CHUNK;     // 144 floats per x1 row
constexpr int X1_LDS = CC * TH * X1RP;      // 2304 floats
constexpr int X2COLS = 104;                 // padded cols stored (need 0..103)
constexpr int X2RP  = (X2COLS / 8) * CHUNK; // 156 floats per x2 row
constexpr int X2_LDS = CC * X2ROWS * X2RP;  // 7488 floats
constexpr int X2_GROUPS = X2COLS / 4;       // 26 float4 groups per padded row
constexpr int X1_F4 = CC * TH * Ww / 4;     // 384 staging items
constexpr int X2_F4 = CC * X2ROWS * X2_GROUPS;  // 1248 items
constexpr int N_ITEMS = X1_F4 + X2_F4;      // 1632 -> <=4 per thread
}

__global__ __launch_bounds__(NT, 2)
void corr81(const float* __restrict__ x1, const float* __restrict__ x2,
            float* __restrict__ out) {
  __shared__ __align__(16) float lds[X1_LDS + X2_LDS + 4];  // +4: dummy f4 slot

  const int t  = threadIdx.x;
  const int y0 = blockIdx.x * TH;
  const int b  = blockIdx.y;
  const int cb = blockIdx.z * CPB;          // channel-half base

  const int r   = t / (NDisp * NSTRIP);     // 0..3  output row within tile
  const int rem = t % (NDisp * NSTRIP);
  const int s   = rem / NDisp;              // 0..11 strip   (dyi fastest)
  const int dyi = rem % NDisp;              // 0..8  (dy+4)
  const int x0  = s * PX;

  const float* __restrict__ x1b = x1 + ((size_t)b * Cch + cb) * HW;
  const float* __restrict__ x2b = x2 + ((size_t)b * Cch + cb) * HW;

  // ---- precompute staging descriptors (constant 4 slots, mask invalid) ----
  const float* gp[4];
  int  loff[4];
  bool zero[4];
#pragma unroll
  for (int j = 0; j < 4; ++j) {
    int i = t + j * NT;
    if (i >= N_ITEMS) {                     // pad slot: write to dummy LDS tail
      gp[j] = x1b; loff[j] = X1_LDS + X2_LDS; zero[j] = true;
    } else if (i < X1_F4) {
      int c    = i / (TH * Ww / 4);         // 96 f4 per channel (4 rows)
      int q    = i % (TH * Ww / 4);
      int grow = q / (Ww / 4);              // 0..3 row in tile
      int col  = (q % (Ww / 4)) * 4;        // 0,4,...,92
      gp[j]   = x1b + c * HW + (size_t)(y0 + grow) * Ww + col;
      loff[j] = c * (TH * X1RP) + grow * X1RP + (col >> 3) * CHUNK + (col & 7);
      zero[j] = false;
    } else {
      int m  = i - X1_F4;
      int c  = m / (X2ROWS * X2_GROUPS);
      int m2 = m % (X2ROWS * X2_GROUPS);
      int ry = m2 / X2_GROUPS;              // 0..11 padded row
      int g  = m2 % X2_GROUPS;              // col group: padded cols [4g,4g+3]
      int pc = g * 4;
      int gy = y0 + ry - Dd;
      bool z = (gy < 0) | (gy >= Hh) | (g == 0) | (g == X2_GROUPS - 1);
      gp[j]   = z ? x2b : (x2b + c * HW + gy * Ww + (pc - 4));
      loff[j] = X1_LDS + c * (X2ROWS * X2RP) + ry * X2RP
              + (pc >> 3) * CHUNK + (pc & 7);
      zero[j] = z;
    }
  }

  float acc[NDisp][PX];
#pragma unroll
  for (int i = 0; i < NDisp; ++i)
#pragma unroll
    for (int j = 0; j < PX; ++j) acc[i][j] = 0.f;

  // per-thread LDS read bases (cc strides folded into ds imm offsets)
  const float* ap0 = lds + r * X1RP + s * CHUNK;
  const float* bp0 = lds + X1_LDS + (r + dyi) * X2RP + s * CHUNK;

  // ---- prefetch stage 0 into registers ----
  float4 v[4];
#pragma unroll
  for (int j = 0; j < 4; ++j)
    v[j] = zero[j] ? make_float4(0.f, 0.f, 0.f, 0.f) : *(const float4*)gp[j];

  for (int c0 = 0; c0 < CPB; c0 += CC) {
    __syncthreads();                        // previous compute done with LDS
    // registers -> LDS, all float4 (chunked layout keeps 16B alignment)
#pragma unroll
    for (int j = 0; j < 4; ++j)
      *(float4*)(lds + loff[j]) = v[j];
    __syncthreads();
    // issue next stage's global loads before compute -> latency overlap
    if (c0 + CC < CPB) {
#pragma unroll
      for (int j = 0; j < 4; ++j) {
        gp[j] += CC * HW;
        v[j] = zero[j] ? make_float4(0.f, 0.f, 0.f, 0.f) : *(const float4*)gp[j];
      }
    }
    // ---- compute: per channel 2 + 4 ds_read_b128, 72 FMAs ----
#pragma unroll
    for (int cc = 0; cc < CC; ++cc) {
      const float* ap = ap0 + cc * (TH * X1RP);
      float a[PX];
      *(float4*)(a)     = *(const float4*)(ap);
      *(float4*)(a + 4) = *(const float4*)(ap + 4);
      const float* bp = bp0 + cc * (X2ROWS * X2RP);
      float bb[PX + 2 * Dd];
      *(float4*)(bb)      = *(const float4*)(bp);             // chunk s   [0..3]
      *(float4*)(bb + 4)  = *(const float4*)(bp + 4);         // chunk s   [4..7]
      *(float4*)(bb + 8)  = *(const float4*)(bp + CHUNK);     // chunk s+1 [0..3]
      *(float4*)(bb + 12) = *(const float4*)(bp + CHUNK + 4); // chunk s+1 [4..7]
#pragma unroll
      for (int dx = 0; dx < NDisp; ++dx)
#pragma unroll
        for (int px = 0; px < PX; ++px)
          acc[dx][px] += a[px] * bb[px + dx];
    }
  }

  // ---- epilogue: accumulate into out (both channel-halves add) ----
  const float nrm = 1.0f / (float)Cch;
  float* ob = out + ((size_t)b * (NDisp * NDisp) + (size_t)dyi * NDisp) * HW
                  + (size_t)(y0 + r) * Ww + x0;
#pragma unroll
  for (int dx = 0; dx < NDisp; ++dx)
#pragma unroll
    for (int px = 0; px < PX; ++px)
      atomicAdd(ob + (size_t)dx * HW + px, acc[dx][px] * nrm);
}

extern "C" void kernel_launch(void* const* d_in, const int* in_sizes, int n_in,
                              void* d_out, int out_size, void* d_ws, size_t ws_size,
                              hipStream_t stream) {
  const float* x1 = (const float*)d_in[0];
  const float* x2 = (const float*)d_in[1];
  float* out = (float*)d_out;
  hipMemsetAsync(d_out, 0, (size_t)out_size, stream);
  dim3 grid(Hh / TH, Bsz, CSPLIT);   // 24 x 16 x 2 = 768 half-blocks
  dim3 block(NT);                    // 432 threads
  hipLaunchKernelGGL(corr81, grid, block, 0, stream, x1, x2, out);
}